// Round 4
// baseline (1053.088 us; speedup 1.0000x reference)
//
#include <hip/hip_runtime.h>
#include <math.h>

#define NN 10000
#define NFEAT 512
#define NHID 256
#define NCLASS 40
#define MAXDEG 64

typedef __attribute__((ext_vector_type(8))) short short8v;   // 8 bf16 (4 VGPR)
typedef __attribute__((ext_vector_type(4))) float floatx4;   // MFMA acc

static __device__ __forceinline__ unsigned short bf16_rne(float f) {
    unsigned u = __builtin_bit_cast(unsigned, f);
    u += 0x7fffu + ((u >> 16) & 1u);
    return (unsigned short)(u >> 16);
}
static __device__ __forceinline__ float bf16_f32(unsigned short h) {
    unsigned u = ((unsigned)h) << 16;
    return __builtin_bit_cast(float, u);
}

// ---------------------------------------------------------------------------
// Fused pack kernel: all three B operands -> MFMA fragment order
//   P[((ks*NTOT + ct)*64 + lane)*8 + j] = B[k][c]
//   k = ks*32 + 8*(lane>>4) + j,  c = ct*16 + (lane&15)
// ---------------------------------------------------------------------------
__global__ __launch_bounds__(256) void pack_all(const float* __restrict__ EW,
                                                const float* __restrict__ W,
                                                const float* __restrict__ DW,
                                                unsigned short* __restrict__ PEh,
                                                unsigned short* __restrict__ PEl,
                                                unsigned short* __restrict__ PWh,
                                                unsigned short* __restrict__ PWl,
                                                unsigned short* __restrict__ PDh,
                                                unsigned short* __restrict__ PDl) {
    int b = blockIdx.x;
    if (b < 512) {                                  // enc: K=512, NTOT=16
        int idx = b * 256 + threadIdx.x;            // 131072
        int j = idx & 7, lane = (idx >> 3) & 63;
        int ctks = idx >> 9;
        int ct = ctks & 15, ks = ctks >> 4;
        int k = ks * 32 + ((lane >> 4) << 3) + j;
        int c = ct * 16 + (lane & 15);
        float w = EW[(size_t)c * NFEAT + k];
        unsigned short h = bf16_rne(w);
        PEh[idx] = h;
        PEl[idx] = bf16_rne(w - bf16_f32(h));
    } else if (b < 768) {                           // layer: K=256, NTOT=16
        int idx = (b - 512) * 256 + threadIdx.x;    // 65536
        int j = idx & 7, lane = (idx >> 3) & 63;
        int ctks = idx >> 9;
        int ct = ctks & 15, ks = ctks >> 4;
        int k = ks * 32 + ((lane >> 4) << 3) + j;
        int c = ct * 16 + (lane & 15);
        float w = 0.25f * (W[k * NHID + c] + W[c * NHID + k]);
        unsigned short h = bf16_rne(w);
        PWh[idx] = h;
        PWl[idx] = bf16_rne(w - bf16_f32(h));
    } else {                                        // dec: K=256, NTOT=3 (48 cols)
        int idx = (b - 768) * 256 + threadIdx.x;    // 12288
        int j = idx & 7, lane = (idx >> 3) & 63;
        int ctks = idx >> 9;
        int ct = ctks % 3, ks = ctks / 3;
        int k = ks * 32 + ((lane >> 4) << 3) + j;
        int c = ct * 16 + (lane & 15);
        float w = (c < NCLASS) ? DW[(size_t)c * NHID + k] : 0.f;
        unsigned short h = bf16_rne(w);
        PDh[idx] = h;
        PDl[idx] = bf16_rne(w - bf16_f32(h));
    }
}

// ---------------------------------------------------------------------------
// MFMA GEMM body (bf16x3 split emulating f32).
// AF32: A loaded from f32 and split in-register; else from Ah/Al bf16 arrays.
// EPI: 0 enc relu(+bias) | 1 layer x+relu(x+acc) (+opt split-out) | 2 dec +bias
// ---------------------------------------------------------------------------
template <int K, int NTOT, int NT, int EPI, int AF32>
static __device__ __forceinline__ void gemm_body(int bx, int by,
                                                 const unsigned short* __restrict__ Ah,
                                                 const unsigned short* __restrict__ Al,
                                                 const float* __restrict__ Af,
                                                 const unsigned short* __restrict__ Ph,
                                                 const unsigned short* __restrict__ Pl,
                                                 const float* __restrict__ aux,
                                                 float* __restrict__ out,
                                                 unsigned short* __restrict__ oh,
                                                 unsigned short* __restrict__ ol,
                                                 int wsplit) {
    int tid = threadIdx.x;
    int wave = tid >> 6, lane = tid & 63;
    int rowA = bx * 64 + wave * 16 + (lane & 15);
    if (rowA >= NN) rowA = NN - 1;                  // clamped loads, guarded stores
    int ct0 = by * NT;
    int koff = (lane >> 4) << 3;

    floatx4 acc[NT];
#pragma unroll
    for (int t = 0; t < NT; ++t) acc[t] = (floatx4){0.f, 0.f, 0.f, 0.f};

#pragma unroll 2
    for (int ks = 0; ks < K / 32; ++ks) {
        short8v a_h, a_l;
        if (AF32) {
            const float* ap = Af + (size_t)rowA * K + ks * 32 + koff;
            float4 v0 = *(const float4*)ap;
            float4 v1 = *(const float4*)(ap + 4);
            float vv[8] = {v0.x, v0.y, v0.z, v0.w, v1.x, v1.y, v1.z, v1.w};
#pragma unroll
            for (int j = 0; j < 8; ++j) {
                unsigned short h = bf16_rne(vv[j]);
                a_h[j] = (short)h;
                a_l[j] = (short)bf16_rne(vv[j] - bf16_f32(h));
            }
        } else {
            a_h = *(const short8v*)(Ah + (size_t)rowA * K + ks * 32 + koff);
            a_l = *(const short8v*)(Al + (size_t)rowA * K + ks * 32 + koff);
        }
        const unsigned short* bph = Ph + ((size_t)(ks * NTOT + ct0) * 64 + lane) * 8;
        const unsigned short* bpl = Pl + ((size_t)(ks * NTOT + ct0) * 64 + lane) * 8;
#pragma unroll
        for (int t = 0; t < NT; ++t) {
            short8v b_h = *(const short8v*)(bph + t * 512);
            short8v b_l = *(const short8v*)(bpl + t * 512);
            acc[t] = __builtin_amdgcn_mfma_f32_16x16x32_bf16(a_h, b_h, acc[t], 0, 0, 0);
            acc[t] = __builtin_amdgcn_mfma_f32_16x16x32_bf16(a_l, b_h, acc[t], 0, 0, 0);
            acc[t] = __builtin_amdgcn_mfma_f32_16x16x32_bf16(a_h, b_l, acc[t], 0, 0, 0);
        }
    }

    // D layout: col = lane&15, row = 4*(lane>>4) + reg
    int rbase = bx * 64 + wave * 16 + ((lane >> 4) << 2);
    int cbase = ct0 * 16 + (lane & 15);
#pragma unroll
    for (int t = 0; t < NT; ++t) {
        int c = cbase + t * 16;
#pragma unroll
        for (int i = 0; i < 4; ++i) {
            int r = rbase + i;
            if (r < NN) {
                float v = acc[t][i];
                if (EPI == 0) {
                    out[(size_t)r * NHID + c] = fmaxf(v + aux[c], 0.f);
                } else if (EPI == 1) {
                    float xv = aux[(size_t)r * NHID + c];
                    float o = xv + fmaxf(xv + v, 0.f);
                    out[(size_t)r * NHID + c] = o;
                    if (wsplit) {
                        unsigned short h = bf16_rne(o);
                        oh[(size_t)r * NHID + c] = h;
                        ol[(size_t)r * NHID + c] = bf16_rne(o - bf16_f32(h));
                    }
                } else {
                    if (c < NCLASS) out[(size_t)r * NCLASS + c] = v + aux[c];
                }
            }
        }
    }
}

// ---------------------------------------------------------------------------
// uber: blocks [0,2500) build ELL adjacency from dense A (HBM-BW bound, 400MB);
//       blocks [2500,2814) run the encoder MFMA GEMM (hides under the scan).
// ---------------------------------------------------------------------------
__global__ __launch_bounds__(256, 2) void uber(const float* __restrict__ A,
                                               int* __restrict__ cols,
                                               int* __restrict__ deg,
                                               float* __restrict__ dinv,
                                               const float* __restrict__ x,
                                               const unsigned short* __restrict__ PEh,
                                               const unsigned short* __restrict__ PEl,
                                               const float* __restrict__ enc_b,
                                               float* __restrict__ X0) {
    int b = blockIdx.x;
    if (b < 2500) {
        int wave = threadIdx.x >> 6;
        int lane = threadIdx.x & 63;
        int row = b * 4 + wave;
        const float4* Arow = (const float4*)(A + (size_t)row * NN);
        int* crow = cols + (size_t)row * MAXDEG;
        int off = 0;
        unsigned long long lmask = (lane == 63) ? 0xFFFFFFFFFFFFFFFFull >> 1
                                                : ((1ull << lane) - 1ull);
        for (int q = lane; q < NN / 4; q += 64) {
            float4 v = Arow[q];
            unsigned long long b0 = __ballot(v.x != 0.f);
            unsigned long long b1 = __ballot(v.y != 0.f);
            unsigned long long b2 = __ballot(v.z != 0.f);
            unsigned long long b3 = __ballot(v.w != 0.f);
            if (v.x != 0.f) { int p = off + __popcll(b0 & lmask); if (p < MAXDEG) crow[p] = 4 * q + 0; }
            off += __popcll(b0);
            if (v.y != 0.f) { int p = off + __popcll(b1 & lmask); if (p < MAXDEG) crow[p] = 4 * q + 1; }
            off += __popcll(b1);
            if (v.z != 0.f) { int p = off + __popcll(b2 & lmask); if (p < MAXDEG) crow[p] = 4 * q + 2; }
            off += __popcll(b2);
            if (v.w != 0.f) { int p = off + __popcll(b3 & lmask); if (p < MAXDEG) crow[p] = 4 * q + 3; }
            off += __popcll(b3);
        }
        if (lane == 0) {
            int d = off < MAXDEG ? off : MAXDEG;
            deg[row] = d;
            dinv[row] = 1.0f / sqrtf((float)(off + 1));
        }
    } else {
        int e = b - 2500;                           // 0..313
        int bx = (e < 157) ? e : e - 157;
        int by = (e < 157) ? 0 : 1;
        gemm_body<NFEAT, 16, 8, 0, 1>(bx, by, nullptr, nullptr, x, PEh, PEl,
                                      enc_b, X0, nullptr, nullptr, 0);
    }
}

// ---------------------------------------------------------------------------
// SpMM: Y[i] = dinv[i]*( dinv[i]*X[i] + sum_{j in N(i)} dinv[j]*X[j] )
// one wave per row; neighbor ids + weights prefetched to registers, __shfl'd
// in the loop so only the X-row gather carries memory latency.
// ---------------------------------------------------------------------------
__global__ __launch_bounds__(256) void spmm(const int* __restrict__ cols,
                                            const int* __restrict__ deg,
                                            const float* __restrict__ dinv,
                                            const float* __restrict__ X,
                                            unsigned short* __restrict__ Yh,
                                            unsigned short* __restrict__ Yl) {
    int wave = threadIdx.x >> 6;
    int lane = threadIdx.x & 63;
    int row = blockIdx.x * 4 + wave;
    if (row >= NN) return;
    int d = deg[row];
    float di = dinv[row];
    const int* crow = cols + (size_t)row * MAXDEG;
    int   c_pre = (lane < d) ? crow[lane] : row;
    float w_pre = (lane < d) ? dinv[c_pre] : 0.f;
    const float4* Xv = (const float4*)X;
    float4 xs = Xv[(size_t)row * 64 + lane];
    float4 acc = make_float4(di * xs.x, di * xs.y, di * xs.z, di * xs.w);
    for (int j = 0; j < d; ++j) {
        int c = __shfl(c_pre, j);
        float w = __shfl(w_pre, j);
        float4 xv = Xv[(size_t)c * 64 + lane];
        acc.x = fmaf(w, xv.x, acc.x);
        acc.y = fmaf(w, xv.y, acc.y);
        acc.z = fmaf(w, xv.z, acc.z);
        acc.w = fmaf(w, xv.w, acc.w);
    }
    float4 o = make_float4(di * acc.x, di * acc.y, di * acc.z, di * acc.w);
    ushort4 h, l;
    h.x = bf16_rne(o.x); l.x = bf16_rne(o.x - bf16_f32(h.x));
    h.y = bf16_rne(o.y); l.y = bf16_rne(o.y - bf16_f32(h.y));
    h.z = bf16_rne(o.z); l.z = bf16_rne(o.z - bf16_f32(h.z));
    h.w = bf16_rne(o.w); l.w = bf16_rne(o.w - bf16_f32(h.w));
    ((ushort4*)Yh)[(size_t)row * 64 + lane] = h;
    ((ushort4*)Yl)[(size_t)row * 64 + lane] = l;
}

__global__ __launch_bounds__(256, 2) void gemm_layer(const unsigned short* __restrict__ Yh,
                                                     const unsigned short* __restrict__ Yl,
                                                     const unsigned short* __restrict__ PWh,
                                                     const unsigned short* __restrict__ PWl,
                                                     const float* __restrict__ Xc,
                                                     float* __restrict__ Xn,
                                                     unsigned short* __restrict__ oh,
                                                     unsigned short* __restrict__ ol,
                                                     int wsplit) {
    gemm_body<NHID, 16, 16, 1, 0>(blockIdx.x, 0, Yh, Yl, nullptr, PWh, PWl,
                                  Xc, Xn, oh, ol, wsplit);
}

__global__ __launch_bounds__(256) void gemm_dec(const unsigned short* __restrict__ Xfh,
                                                const unsigned short* __restrict__ Xfl,
                                                const unsigned short* __restrict__ PDh,
                                                const unsigned short* __restrict__ PDl,
                                                const float* __restrict__ dec_b,
                                                float* __restrict__ out) {
    gemm_body<NHID, 3, 3, 2, 0>(blockIdx.x, 0, Xfh, Xfl, nullptr, PDh, PDl,
                                dec_b, out, nullptr, nullptr, 0);
}

// ---------------------------------------------------------------------------
extern "C" void kernel_launch(void* const* d_in, const int* in_sizes, int n_in,
                              void* d_out, int out_size, void* d_ws, size_t ws_size,
                              hipStream_t stream) {
    const float* x      = (const float*)d_in[0];
    const float* A      = (const float*)d_in[1];
    const float* enc_w  = (const float*)d_in[2];
    const float* enc_b  = (const float*)d_in[3];
    const float* conv_w = (const float*)d_in[4];
    const float* dec_w  = (const float*)d_in[5];
    const float* dec_b  = (const float*)d_in[6];
    float* out = (float*)d_out;

    char* w = (char*)d_ws;
    auto alloc = [&](size_t bytes) {
        char* p = w;
        w += (bytes + 255) & ~(size_t)255;
        return p;
    };
    int*            cols = (int*)alloc((size_t)NN * MAXDEG * 4);
    int*            deg  = (int*)alloc((size_t)NN * 4);
    float*          dinv = (float*)alloc((size_t)NN * 4);
    unsigned short* PEh  = (unsigned short*)alloc((size_t)NFEAT * NHID * 2);
    unsigned short* PEl  = (unsigned short*)alloc((size_t)NFEAT * NHID * 2);
    unsigned short* PWh  = (unsigned short*)alloc((size_t)NHID * NHID * 2);
    unsigned short* PWl  = (unsigned short*)alloc((size_t)NHID * NHID * 2);
    unsigned short* PDh  = (unsigned short*)alloc((size_t)NHID * 48 * 2);
    unsigned short* PDl  = (unsigned short*)alloc((size_t)NHID * 48 * 2);
    float*          Xa   = (float*)alloc((size_t)NN * NHID * 4);
    float*          Xb   = (float*)alloc((size_t)NN * NHID * 4);
    unsigned short* Yh   = (unsigned short*)alloc((size_t)NN * NHID * 2);
    unsigned short* Yl   = (unsigned short*)alloc((size_t)NN * NHID * 2);
    unsigned short* Xfh  = (unsigned short*)alloc((size_t)NN * NHID * 2);
    unsigned short* Xfl  = (unsigned short*)alloc((size_t)NN * NHID * 2);

    pack_all<<<816, 256, 0, stream>>>(enc_w, conv_w, dec_w,
                                      PEh, PEl, PWh, PWl, PDh, PDl);
    uber<<<2500 + 314, 256, 0, stream>>>(A, cols, deg, dinv,
                                         x, PEh, PEl, enc_b, Xa);

    float* Xcur = Xa;
    float* Xnxt = Xb;
    for (int layer = 0; layer < 4; ++layer) {
        spmm<<<2500, 256, 0, stream>>>(cols, deg, dinv, Xcur, Yh, Yl);
        gemm_layer<<<157, 256, 0, stream>>>(Yh, Yl, PWh, PWl, Xcur, Xnxt,
                                            Xfh, Xfl, layer == 3 ? 1 : 0);
        float* t = Xcur; Xcur = Xnxt; Xnxt = t;
    }
    gemm_dec<<<157, 256, 0, stream>>>(Xfh, Xfl, PDh, PDl, dec_b, out);
}